// Round 3
// baseline (292.690 us; speedup 1.0000x reference)
//
#include <hip/hip_runtime.h>
#include <math.h>

#define EMBED   128
#define NHEADS  8
#define NPOINTS 4
#define HD      16
#define HSP     51
#define WSP     102
#define NPIX    (HSP * WSP)   // 5202
#define NQ      10000
#define NLVL    50

// ---------------------------------------------------------------------------
// Fused prep kernel.
// Round-6: value blocks additionally produce the per-head logit map
//   g[pix][h] = sum_{ch in head h} vproj[pix][ch] * u[ch],  u = W_out @ W_proj
// u is computed in-block by lanes t<32 (4 columns each) into LDS.
//   blocks [0, 651)        : value projection + g map, 8 pixels/block
//   blocks [651, 651+1250) : offsets + attention, 8 queries/block
// ---------------------------------------------------------------------------
#define GRID_A ((NPIX + 7) / 8)   // 651
#define GRID_B (NQ / 8)           // 1250

__global__ __launch_bounds__(256) void k_prep(
    const float* __restrict__ value,
    const float* __restrict__ Wv,
    const float* __restrict__ bv,
    const float* __restrict__ query,
    const float* __restrict__ Woff,
    const float* __restrict__ boff,
    const float* __restrict__ Wattn,
    const float* __restrict__ battn,
    const float* __restrict__ Wout,
    const float* __restrict__ Wproj,
    float* __restrict__ vout,     // (NPIX, 128) pixel-major
    float* __restrict__ gout,     // (NPIX, 8) per-head logit map
    float* __restrict__ off_out,
    float* __restrict__ aw_out) {
    const int b = blockIdx.x;
    const int t = threadIdx.x;
    __shared__ float srow[8][EMBED];   // 4 KB: value rows or query rows
    __shared__ float4 u_s[32];

    if (b < GRID_A) {  // ---- value projection + g map ----
        const int p   = t >> 5;        // pixel slot 0..7
        const int s   = t & 31;        // column group (4 cols each)
        const int pix = b * 8 + p;
        const int pl  = min(pix, NPIX - 1);   // clamp loads for the tail block
        *(float4*)&srow[p][s * 4] =
            *(const float4*)(value + (size_t)pl * EMBED + s * 4);
        if (t < 32) {
            // u[t*4+j] = sum_d Wout[t*4+j][d] * Wproj[d]
            float4 u4 = {0.f, 0.f, 0.f, 0.f};
            const float* w0 = Wout + (size_t)(t * 4 + 0) * EMBED;
            const float* w1 = Wout + (size_t)(t * 4 + 1) * EMBED;
            const float* w2 = Wout + (size_t)(t * 4 + 2) * EMBED;
            const float* w3 = Wout + (size_t)(t * 4 + 3) * EMBED;
#pragma unroll 4
            for (int d = 0; d < EMBED; d += 4) {
                const float4 wp = *(const float4*)(Wproj + d);
                const float4 a = *(const float4*)(w0 + d);
                const float4 c = *(const float4*)(w1 + d);
                const float4 e = *(const float4*)(w2 + d);
                const float4 f = *(const float4*)(w3 + d);
                u4.x = fmaf(a.x, wp.x, u4.x); u4.x = fmaf(a.y, wp.y, u4.x);
                u4.x = fmaf(a.z, wp.z, u4.x); u4.x = fmaf(a.w, wp.w, u4.x);
                u4.y = fmaf(c.x, wp.x, u4.y); u4.y = fmaf(c.y, wp.y, u4.y);
                u4.y = fmaf(c.z, wp.z, u4.y); u4.y = fmaf(c.w, wp.w, u4.y);
                u4.z = fmaf(e.x, wp.x, u4.z); u4.z = fmaf(e.y, wp.y, u4.z);
                u4.z = fmaf(e.z, wp.z, u4.z); u4.z = fmaf(e.w, wp.w, u4.z);
                u4.w = fmaf(f.x, wp.x, u4.w); u4.w = fmaf(f.y, wp.y, u4.w);
                u4.w = fmaf(f.z, wp.z, u4.w); u4.w = fmaf(f.w, wp.w, u4.w);
            }
            u_s[t] = u4;
        }
        __syncthreads();
        float4 acc = *(const float4*)(bv + s * 4);
        const float* vr = srow[p];
        const float* wp = Wv + s * 4;
#pragma unroll 8
        for (int k = 0; k < EMBED; ++k) {
            const float qv = vr[k];
            const float4 w4 = *(const float4*)(wp + (size_t)k * EMBED);
            acc.x = fmaf(qv, w4.x, acc.x);
            acc.y = fmaf(qv, w4.y, acc.y);
            acc.z = fmaf(qv, w4.z, acc.z);
            acc.w = fmaf(qv, w4.w, acc.w);
        }
        // per-head logit-map partial: this lane covers 4 channels of head s>>2
        const float4 u4 = u_s[s];
        float gp = acc.x * u4.x;
        gp = fmaf(acc.y, u4.y, gp);
        gp = fmaf(acc.z, u4.z, gp);
        gp = fmaf(acc.w, u4.w, gp);
        gp += __shfl_xor(gp, 1, 64);
        gp += __shfl_xor(gp, 2, 64);   // sum over the 4 lanes of this head
        if (pix < NPIX) {
            *(float4*)(vout + (size_t)pix * EMBED + s * 4) = acc;
            if ((s & 3) == 0)
                gout[(size_t)pix * NHEADS + (s >> 2)] = gp;
        }
    } else if (b < GRID_A + GRID_B) {  // ---- offsets + attention ----
        const int qi = t >> 5;         // query slot 0..7
        const int s  = t & 31;
        const int q  = (b - GRID_A) * 8 + qi;
        *(float4*)&srow[qi][s * 4] =
            *(const float4*)(query + (size_t)q * EMBED + s * 4);
        __syncthreads();
        if (s < 24) {                  // lanes 0-15: offsets, 16-23: attn
            const float* vr = srow[qi];
            const float* wp;
            int wstride;
            float4 acc;
            if (s < 16) {
                wp = Woff + s * 4; wstride = 64;
                acc = *(const float4*)(boff + s * 4);
            } else {
                wp = Wattn + (s - 16) * 4; wstride = 32;
                acc = *(const float4*)(battn + (s - 16) * 4);
            }
#pragma unroll 8
            for (int k = 0; k < EMBED; ++k) {
                const float qv = vr[k];
                const float4 w4 = *(const float4*)(wp + (size_t)k * wstride);
                acc.x = fmaf(qv, w4.x, acc.x);
                acc.y = fmaf(qv, w4.y, acc.y);
                acc.z = fmaf(qv, w4.z, acc.z);
                acc.w = fmaf(qv, w4.w, acc.w);
            }
            if (s < 16) {
                *(float4*)(off_out + (size_t)q * 64 + s * 4) = acc;
            } else {
                const float mx = fmaxf(fmaxf(acc.x, acc.y), fmaxf(acc.z, acc.w));
                const float e0 = __expf(acc.x - mx), e1 = __expf(acc.y - mx);
                const float e2 = __expf(acc.z - mx), e3 = __expf(acc.w - mx);
                const float inv = 1.f / (e0 + e1 + e2 + e3);
                float4 r;
                r.x = e0 * inv; r.y = e1 * inv; r.z = e2 * inv; r.w = e3 * inv;
                *(float4*)(aw_out + (size_t)q * 32 + (s - 16) * 4) = r;
            }
        }
    }
}

// ---------------------------------------------------------------------------
// Main kernel, round-6: phase-split.
// Phase A: all level logits via the scalar per-head g map (each lane owns one
//   (h,p) pair, 4 scalar gathers + one 5-step reduce per level; 13 independent
//   chains pipeline). Produces e_l, Z, m, best; e goes to a small LDS array
//   (written and read by the same wave -> no barrier).
// Phase B: gather + accumulate only — no dot, no shuffles, no exp in the
//   critical loop.
// Merges and epilogue unchanged from round-5.
// NOTE: the half-merge MUST also merge m (m = fmaxf(m, mo)) — the cross-wave
// merge consumes m as the comparison key (round-3 bug).
// ---------------------------------------------------------------------------
__global__ __launch_bounds__(256, 6) void k_main(
    const float* __restrict__ query,
    const float* __restrict__ refp,   // (NLVL, NQ, 2)
    const float* __restrict__ voff,   // (NQ, 8, 4, 2)
    const float* __restrict__ vaw,    // (NQ, 8, 4)
    const float* __restrict__ vflat,  // (NPIX, 128) pixel-major
    const float* __restrict__ gmap,   // (NPIX, 8) per-head logit map
    const float* __restrict__ Wout,   // (128, 128)
    const float* __restrict__ bout,   // (128)
    float* __restrict__ out0,         // (NQ, 128)
    float* __restrict__ out1) {       // (NQ) argmax level, as float
    const int t = threadIdx.x;
    const int qslot = t >> 7;         // 0..1
    const int w2 = (t >> 6) & 1;      // wave index within query
    const int half = (t >> 5) & 1;
    const int sub = t & 31;
    const int h  = sub >> 2;
    const int c4 = sub & 3;
    const int q = blockIdx.x * 2 + qslot;

    __shared__ float  s_rpy[2][NLVL];
    __shared__ float4 s_acc[2][32];
    __shared__ float  s_z[2], s_m[2];
    __shared__ int    s_b[2];
    __shared__ float  s_e[2][2][2][13];   // [qslot][w2][half][i]

    // cooperative preload of ref.y for this block's 2 queries
    if (t < 2 * NLVL) {
        const int ql = t / NLVL, l = t - ql * NLVL;
        const int qq = blockIdx.x * 2 + ql;
        s_rpy[ql][l] = refp[((size_t)l * NQ + qq) * 2 + 1];
    }

    const float4* offp = (const float4*)(voff + (size_t)q * 64 + h * 8);
    const float4 o01 = offp[0];       // p0.x p0.y p1.x p1.y
    const float4 o23 = offp[1];
    const float4 awv4 = *(const float4*)(vaw + (size_t)q * 32 + h * 4);
    const float rpx = refp[(size_t)q * 2];   // col is level-invariant
    // lane-fixed channel slot within a 32-float4 pixel record
    const float4* vbase = (const float4*)vflat + h * 4 + c4;

    const float offx[4] = {o01.x, o01.z, o23.x, o23.z};
    const float offy[4] = {o01.y, o01.w, o23.y, o23.w};
    const float awv[4]  = {awv4.x, awv4.y, awv4.z, awv4.w};

    // level-independent x-axis state per point (pixel stride = 32 float4)
    float wx0[NPOINTS], wx1[NPOINTS], oyc[NPOINTS];
    int xo0[NPOINTS], xo1[NPOINTS];
#pragma unroll
    for (int p = 0; p < NPOINTS; ++p) {
        const float px = fmaf(rpx, (float)WSP, offx[p]) - 0.5f;
        const float fx = floorf(px);
        const float dx = px - fx;
        const int x0 = (int)fx, x1 = x0 + 1;
        const float a = awv[p];
        wx0[p] = ((unsigned)x0 < (unsigned)WSP) ? a * (1.f - dx) : 0.f;
        wx1[p] = ((unsigned)x1 < (unsigned)WSP) ? a * dx : 0.f;
        xo0[p] = min(max(x0, 0), WSP - 1) * 32;
        xo1[p] = min(max(x1, 0), WSP - 1) * 32;
        oyc[p] = offy[p] - 0.5f;
    }

    // this lane's own (h, p=c4) point, scalar x-state for the g map
    const float offx_c = (c4 == 0) ? o01.x : (c4 == 1) ? o01.z : (c4 == 2) ? o23.x : o23.z;
    const float offy_c = (c4 == 0) ? o01.y : (c4 == 1) ? o01.w : (c4 == 2) ? o23.y : o23.w;
    const float a_c    = (c4 == 0) ? awv4.x : (c4 == 1) ? awv4.y : (c4 == 2) ? awv4.z : awv4.w;
    const float pxc = fmaf(rpx, (float)WSP, offx_c) - 0.5f;
    const float fxc = floorf(pxc);
    const float dxc = pxc - fxc;
    const int x0c = (int)fxc, x1c = x0c + 1;
    const float gwx0 = ((unsigned)x0c < (unsigned)WSP) ? a_c * (1.f - dxc) : 0.f;
    const float gwx1 = ((unsigned)x1c < (unsigned)WSP) ? a_c * dxc : 0.f;
    const int gx0 = min(max(x0c, 0), WSP - 1) * NHEADS + h;
    const int gx1 = min(max(x1c, 0), WSP - 1) * NHEADS + h;
    const float oyc_c = offy_c - 0.5f;

    __syncthreads();

    const int niter = 13 - w2;        // w2=0: 13 iters, w2=1: 12
    float Z = 0.f, m = -1e30f;
    int best = 0;

    // ---- Phase A: logits / softmax numerators via the g map ----
#pragma unroll
    for (int i = 0; i < 13; ++i) {
        if (i >= niter) break;
        const int l = 4 * i + (w2 << 1) + half;
        const float rpy = s_rpy[qslot][l];
        const float py = fmaf(rpy, (float)HSP, oyc_c);
        const float fy = floorf(py);
        const float dy = py - fy;
        const int y0 = (int)fy, y1 = y0 + 1;
        const float t0 = ((unsigned)y0 < (unsigned)HSP) ? (1.f - dy) : 0.f;
        const float t1 = ((unsigned)y1 < (unsigned)HSP) ? dy : 0.f;
        const int r0 = min(max(y0, 0), HSP - 1) * (WSP * NHEADS);
        const int r1 = min(max(y1, 0), HSP - 1) * (WSP * NHEADS);
        const float g00 = gmap[r0 + gx0];
        const float g01 = gmap[r0 + gx1];
        const float g10 = gmap[r1 + gx0];
        const float g11 = gmap[r1 + gx1];
        float row0 = gwx0 * g00; row0 = fmaf(gwx1, g01, row0);
        float row1 = gwx0 * g10; row1 = fmaf(gwx1, g11, row1);
        float pg = t0 * row0; pg = fmaf(t1, row1, pg);
#pragma unroll
        for (int d = 1; d < 32; d <<= 1)
            pg += __shfl_xor(pg, d, 64);
        const float e = __expf(pg);
        Z += e;
        best = (pg > m) ? l : best;   // strict > : first occurrence wins
        m = fmaxf(pg, m);
        if (sub == 0) s_e[qslot][w2][half][i] = e;
    }

    float4 acc = {0.f, 0.f, 0.f, 0.f};

    // ---- Phase B: gather + accumulate (no cross-lane ops) ----
#pragma unroll 1
    for (int i = 0; i < niter; ++i) {
        const int l = 4 * i + (w2 << 1) + half;
        const float rpy = s_rpy[qslot][l];

        float4 v00[NPOINTS], v01[NPOINTS], v10[NPOINTS], v11[NPOINTS];
        float w00[NPOINTS], w01[NPOINTS], w10[NPOINTS], w11[NPOINTS];
#pragma unroll
        for (int p = 0; p < NPOINTS; ++p) {
            const float py = fmaf(rpy, (float)HSP, oyc[p]);
            const float fy = floorf(py);
            const float dy = py - fy;
            const int y0 = (int)fy, y1 = y0 + 1;
            const float t0 = ((unsigned)y0 < (unsigned)HSP) ? (1.f - dy) : 0.f;
            const float t1 = ((unsigned)y1 < (unsigned)HSP) ? dy : 0.f;
            const int rb0 = min(max(y0, 0), HSP - 1) * (WSP * 32);
            const int rb1 = min(max(y1, 0), HSP - 1) * (WSP * 32);
            v00[p] = vbase[rb0 + xo0[p]];
            v01[p] = vbase[rb0 + xo1[p]];
            v10[p] = vbase[rb1 + xo0[p]];
            v11[p] = vbase[rb1 + xo1[p]];
            w00[p] = wx0[p] * t0;
            w01[p] = wx1[p] * t0;
            w10[p] = wx0[p] * t1;
            w11[p] = wx1[p] * t1;
        }
        float4 s = {0.f, 0.f, 0.f, 0.f};
#pragma unroll
        for (int p = 0; p < NPOINTS; ++p) {
            s.x = fmaf(w00[p], v00[p].x, s.x); s.y = fmaf(w00[p], v00[p].y, s.y);
            s.z = fmaf(w00[p], v00[p].z, s.z); s.w = fmaf(w00[p], v00[p].w, s.w);
            s.x = fmaf(w01[p], v01[p].x, s.x); s.y = fmaf(w01[p], v01[p].y, s.y);
            s.z = fmaf(w01[p], v01[p].z, s.z); s.w = fmaf(w01[p], v01[p].w, s.w);
            s.x = fmaf(w10[p], v10[p].x, s.x); s.y = fmaf(w10[p], v10[p].y, s.y);
            s.z = fmaf(w10[p], v10[p].z, s.z); s.w = fmaf(w10[p], v10[p].w, s.w);
            s.x = fmaf(w11[p], v11[p].x, s.x); s.y = fmaf(w11[p], v11[p].y, s.y);
            s.z = fmaf(w11[p], v11[p].z, s.z); s.w = fmaf(w11[p], v11[p].w, s.w);
        }
        const float e = s_e[qslot][w2][half][i];
        acc.x = fmaf(e, s.x, acc.x);
        acc.y = fmaf(e, s.y, acc.y);
        acc.z = fmaf(e, s.z, acc.z);
        acc.w = fmaf(e, s.w, acc.w);
    }

    // merge the two halves of this wave (exact: plain sums, no rescale)
    {
        const float mo = __shfl_xor(m, 32, 64);
        const int   bo = __shfl_xor(best, 32, 64);
        const float Zo = __shfl_xor(Z, 32, 64);
        const float ax = __shfl_xor(acc.x, 32, 64);
        const float ay = __shfl_xor(acc.y, 32, 64);
        const float az = __shfl_xor(acc.z, 32, 64);
        const float aw_ = __shfl_xor(acc.w, 32, 64);
        const bool takeOther = (mo > m) || (mo == m && bo < best);
        best = takeOther ? bo : best;
        m = fmaxf(m, mo);               // <- merge the key too (round-3 fix)
        Z += Zo;
        acc.x += ax; acc.y += ay; acc.z += az; acc.w += aw_;
    }

    // wave 1 publishes its partials; wave 0 merges and finishes
    if (w2 == 1) {
        if (half == 0) s_acc[qslot][sub] = acc;
        if ((t & 63) == 0) { s_z[qslot] = Z; s_m[qslot] = m; s_b[qslot] = best; }
    }
    __syncthreads();

    if (w2 == 0) {
        const float4 ao = s_acc[qslot][sub];
        const float Zo = s_z[qslot];
        const float mo = s_m[qslot];
        const int   bo = s_b[qslot];
        const bool takeOther = (mo > m) || (mo == m && bo < best);
        best = takeOther ? bo : best;
        Z += Zo;
        acc.x += ao.x; acc.y += ao.y; acc.z += ao.z; acc.w += ao.w;

        const float inv = 1.f / Z;
        if (half == 0) {
            float4 sv;
            sv.x = acc.x * inv; sv.y = acc.y * inv;
            sv.z = acc.z * inv; sv.w = acc.w * inv;
            s_acc[qslot][sub] = sv;       // channel-group index == sub
            if (sub == 0) out1[q] = (float)best;
        }
        // same-wave DS ordering makes the write visible to both halves below

        // final: out[dp] = sum_c s[c]*Wout[c][dp] + bout[dp] + 2*query[q][dp]
        // split-K across the two halves: half0 sums cg 0..15, half1 cg 16..31
        const int dpb = sub * 4;
        float4 r = {0.f, 0.f, 0.f, 0.f};
        if (half == 0) {
            const float4 b4 = *(const float4*)(bout + dpb);
            const float4 q4 = *(const float4*)(query + (size_t)q * EMBED + dpb);
            r.x = fmaf(2.f, q4.x, b4.x);
            r.y = fmaf(2.f, q4.y, b4.y);
            r.z = fmaf(2.f, q4.z, b4.z);
            r.w = fmaf(2.f, q4.w, b4.w);
        }
        const float4* srow = s_acc[qslot];
        const int cg0 = half * 16;
#pragma unroll 4
        for (int cg = cg0; cg < cg0 + 16; ++cg) {
            const float4 s4 = srow[cg];
            const float4 w0 = *(const float4*)(Wout + (size_t)(cg * 4 + 0) * EMBED + dpb);
            const float4 w1 = *(const float4*)(Wout + (size_t)(cg * 4 + 1) * EMBED + dpb);
            const float4 w2v = *(const float4*)(Wout + (size_t)(cg * 4 + 2) * EMBED + dpb);
            const float4 w3 = *(const float4*)(Wout + (size_t)(cg * 4 + 3) * EMBED + dpb);
            r.x = fmaf(s4.x, w0.x, r.x); r.y = fmaf(s4.x, w0.y, r.y);
            r.z = fmaf(s4.x, w0.z, r.z); r.w = fmaf(s4.x, w0.w, r.w);
            r.x = fmaf(s4.y, w1.x, r.x); r.y = fmaf(s4.y, w1.y, r.y);
            r.z = fmaf(s4.y, w1.z, r.z); r.w = fmaf(s4.y, w1.w, r.w);
            r.x = fmaf(s4.z, w2v.x, r.x); r.y = fmaf(s4.z, w2v.y, r.y);
            r.z = fmaf(s4.z, w2v.z, r.z); r.w = fmaf(s4.z, w2v.w, r.w);
            r.x = fmaf(s4.w, w3.x, r.x); r.y = fmaf(s4.w, w3.y, r.y);
            r.z = fmaf(s4.w, w3.z, r.z); r.w = fmaf(s4.w, w3.w, r.w);
        }
        // combine the two half-sums and store from half 0
        {
            const float rx = __shfl_xor(r.x, 32, 64);
            const float ry = __shfl_xor(r.y, 32, 64);
            const float rz = __shfl_xor(r.z, 32, 64);
            const float rw = __shfl_xor(r.w, 32, 64);
            r.x += rx; r.y += ry; r.z += rz; r.w += rw;
        }
        if (half == 0)
            *(float4*)(out0 + (size_t)q * EMBED + dpb) = r;
    }
}

// ---------------------------------------------------------------------------
extern "C" void kernel_launch(void* const* d_in, const int* in_sizes, int n_in,
                              void* d_out, int out_size, void* d_ws, size_t ws_size,
                              hipStream_t stream) {
    const float* query = (const float*)d_in[0];
    const float* value = (const float*)d_in[1];
    const float* refp  = (const float*)d_in[2];
    const float* Woff  = (const float*)d_in[3];
    const float* boff  = (const float*)d_in[4];
    const float* Wattn = (const float*)d_in[5];
    const float* battn = (const float*)d_in[6];
    const float* Wval  = (const float*)d_in[7];
    const float* bval  = (const float*)d_in[8];
    const float* Wout  = (const float*)d_in[9];
    const float* bout  = (const float*)d_in[10];
    const float* Wproj = (const float*)d_in[11];
    // d_in[12] = b_proj: level-constant -> cancels in softmax/argmax, unused.

    float* ws = (float*)d_ws;
    float* ws_v   = ws;                                   // NPIX*128 (pixel-major)
    float* ws_g   = ws_v + (size_t)NPIX * EMBED;          // NPIX*8
    float* ws_off = ws_g + (size_t)NPIX * NHEADS;         // NQ*64
    float* ws_aw  = ws_off + (size_t)NQ * 64;             // NQ*32

    float* out0 = (float*)d_out;
    float* out1 = out0 + (size_t)NQ * EMBED;

    hipLaunchKernelGGL(k_prep, dim3(GRID_A + GRID_B), dim3(256), 0, stream,
                       value, Wval, bval, query, Woff, boff, Wattn, battn,
                       Wout, Wproj, ws_v, ws_g, ws_off, ws_aw);
    hipLaunchKernelGGL(k_main, dim3(NQ / 2), dim3(256), 0, stream,
                       query, refp, ws_off, ws_aw, ws_v, ws_g, Wout, bout,
                       out0, out1);
}

// Round 5
// 286.286 us; speedup vs baseline: 1.0224x; 1.0224x over previous
//
#include <hip/hip_runtime.h>
#include <hip/hip_fp16.h>
#include <math.h>

#define EMBED   128
#define NHEADS  8
#define NPOINTS 4
#define HD      16
#define HSP     51
#define WSP     102
#define NPIX    (HSP * WSP)   // 5202
#define NQ      10000
#define NLVL    50

// 8-byte vector of 4 halves: one lane's 4-channel slot of a pixel record.
struct h4v { __half2 a; __half2 b; };

__device__ __forceinline__ float4 h4_to_f4(h4v v) {
    const float2 lo = __half22float2(v.a);
    const float2 hi = __half22float2(v.b);
    float4 r; r.x = lo.x; r.y = lo.y; r.z = hi.x; r.w = hi.y;
    return r;
}

// ---------------------------------------------------------------------------
// Fused prep kernel.
// Round-8: value blocks produce BOTH the fp16 pixel-major value map (for the
// accumulation path; out0 tolerance 0.03125 >> fp16 error ~1e-4) AND the
// fp32 per-head logit map g[pix][h] = sum_{ch in head h} vproj[pix][ch]*u[ch]
// (u = W_out @ W_proj, computed in-block). The logit/argmax path must be
// fp32: round-4 showed fp16-derived logits flip near-tied argmaxes.
//   blocks [0, 651)        : value projection + g map, 8 pixels/block
//   blocks [651, 651+1250) : offsets + attention, 8 queries/block
// ---------------------------------------------------------------------------
#define GRID_A ((NPIX + 7) / 8)   // 651
#define GRID_B (NQ / 8)           // 1250

__global__ __launch_bounds__(256) void k_prep(
    const float* __restrict__ value,
    const float* __restrict__ Wv,
    const float* __restrict__ bv,
    const float* __restrict__ query,
    const float* __restrict__ Woff,
    const float* __restrict__ boff,
    const float* __restrict__ Wattn,
    const float* __restrict__ battn,
    const float* __restrict__ Wout,
    const float* __restrict__ Wproj,
    __half* __restrict__ vout,    // (NPIX, 128) pixel-major fp16
    float* __restrict__ gout,     // (NPIX, 8) per-head fp32 logit map
    float* __restrict__ off_out,
    float* __restrict__ aw_out) {
    const int b = blockIdx.x;
    const int t = threadIdx.x;
    __shared__ float srow[8][EMBED];   // 4 KB: value rows or query rows
    __shared__ float4 u_s[32];

    if (b < GRID_A) {  // ---- value projection + g map ----
        const int p   = t >> 5;        // pixel slot 0..7
        const int s   = t & 31;        // column group (4 cols each)
        const int pix = b * 8 + p;
        const int pl  = min(pix, NPIX - 1);   // clamp loads for the tail block
        *(float4*)&srow[p][s * 4] =
            *(const float4*)(value + (size_t)pl * EMBED + s * 4);
        if (t < 32) {
            // u[t*4+j] = sum_d Wout[t*4+j][d] * Wproj[d]
            float4 u4 = {0.f, 0.f, 0.f, 0.f};
            const float* w0 = Wout + (size_t)(t * 4 + 0) * EMBED;
            const float* w1 = Wout + (size_t)(t * 4 + 1) * EMBED;
            const float* w2 = Wout + (size_t)(t * 4 + 2) * EMBED;
            const float* w3 = Wout + (size_t)(t * 4 + 3) * EMBED;
#pragma unroll 4
            for (int d = 0; d < EMBED; d += 4) {
                const float4 wp = *(const float4*)(Wproj + d);
                const float4 a = *(const float4*)(w0 + d);
                const float4 c = *(const float4*)(w1 + d);
                const float4 e = *(const float4*)(w2 + d);
                const float4 f = *(const float4*)(w3 + d);
                u4.x = fmaf(a.x, wp.x, u4.x); u4.x = fmaf(a.y, wp.y, u4.x);
                u4.x = fmaf(a.z, wp.z, u4.x); u4.x = fmaf(a.w, wp.w, u4.x);
                u4.y = fmaf(c.x, wp.x, u4.y); u4.y = fmaf(c.y, wp.y, u4.y);
                u4.y = fmaf(c.z, wp.z, u4.y); u4.y = fmaf(c.w, wp.w, u4.y);
                u4.z = fmaf(e.x, wp.x, u4.z); u4.z = fmaf(e.y, wp.y, u4.z);
                u4.z = fmaf(e.z, wp.z, u4.z); u4.z = fmaf(e.w, wp.w, u4.z);
                u4.w = fmaf(f.x, wp.x, u4.w); u4.w = fmaf(f.y, wp.y, u4.w);
                u4.w = fmaf(f.z, wp.z, u4.w); u4.w = fmaf(f.w, wp.w, u4.w);
            }
            u_s[t] = u4;
        }
        __syncthreads();
        float4 acc = *(const float4*)(bv + s * 4);
        const float* vr = srow[p];
        const float* wp = Wv + s * 4;
#pragma unroll 8
        for (int k = 0; k < EMBED; ++k) {
            const float qv = vr[k];
            const float4 w4 = *(const float4*)(wp + (size_t)k * EMBED);
            acc.x = fmaf(qv, w4.x, acc.x);
            acc.y = fmaf(qv, w4.y, acc.y);
            acc.z = fmaf(qv, w4.z, acc.z);
            acc.w = fmaf(qv, w4.w, acc.w);
        }
        // per-head logit-map partial from the PRE-ROUNDING fp32 acc
        const float4 u4 = u_s[s];
        float gp = acc.x * u4.x;
        gp = fmaf(acc.y, u4.y, gp);
        gp = fmaf(acc.z, u4.z, gp);
        gp = fmaf(acc.w, u4.w, gp);
        gp += __shfl_xor(gp, 1, 64);
        gp += __shfl_xor(gp, 2, 64);   // sum over the 4 lanes of this head
        if (pix < NPIX) {
            h4v hv;
            hv.a = __floats2half2_rn(acc.x, acc.y);
            hv.b = __floats2half2_rn(acc.z, acc.w);
            *(h4v*)(vout + (size_t)pix * EMBED + s * 4) = hv;
            if ((s & 3) == 0)
                gout[(size_t)pix * NHEADS + (s >> 2)] = gp;
        }
    } else if (b < GRID_A + GRID_B) {  // ---- offsets + attention ----
        const int qi = t >> 5;         // query slot 0..7
        const int s  = t & 31;
        const int q  = (b - GRID_A) * 8 + qi;
        *(float4*)&srow[qi][s * 4] =
            *(const float4*)(query + (size_t)q * EMBED + s * 4);
        __syncthreads();
        if (s < 24) {                  // lanes 0-15: offsets, 16-23: attn
            const float* vr = srow[qi];
            const float* wp;
            int wstride;
            float4 acc;
            if (s < 16) {
                wp = Woff + s * 4; wstride = 64;
                acc = *(const float4*)(boff + s * 4);
            } else {
                wp = Wattn + (s - 16) * 4; wstride = 32;
                acc = *(const float4*)(battn + (s - 16) * 4);
            }
#pragma unroll 8
            for (int k = 0; k < EMBED; ++k) {
                const float qv = vr[k];
                const float4 w4 = *(const float4*)(wp + (size_t)k * wstride);
                acc.x = fmaf(qv, w4.x, acc.x);
                acc.y = fmaf(qv, w4.y, acc.y);
                acc.z = fmaf(qv, w4.z, acc.z);
                acc.w = fmaf(qv, w4.w, acc.w);
            }
            if (s < 16) {
                *(float4*)(off_out + (size_t)q * 64 + s * 4) = acc;
            } else {
                const float mx = fmaxf(fmaxf(acc.x, acc.y), fmaxf(acc.z, acc.w));
                const float e0 = __expf(acc.x - mx), e1 = __expf(acc.y - mx);
                const float e2 = __expf(acc.z - mx), e3 = __expf(acc.w - mx);
                const float inv = 1.f / (e0 + e1 + e2 + e3);
                float4 r;
                r.x = e0 * inv; r.y = e1 * inv; r.z = e2 * inv; r.w = e3 * inv;
                *(float4*)(aw_out + (size_t)q * 32 + (s - 16) * 4) = r;
            }
        }
    }
}

// ---------------------------------------------------------------------------
// Main kernel. Round-8: round-2's FUSED loop structure (gather + logit +
// online softmax per iteration — the fusion IS the latency overlap; round-3's
// phase split regressed). Changes vs round-2:
//  * vflat is fp16 pixel-major -> 16x 8 B corner loads (half the L1 bytes
//    and lines); converted to f32 at consume time (v_fma_mix-able).
//  * logit comes from the fp32 gmap (round-3's exact per-lane formula +
//    5-step shuffle reduce — proven argmax-safe), gathered IN the loop:
//    4 scalar loads for this lane's own (h, p=c4) point.
// NOTE: the half-merge MUST also merge m (m = fmaxf(m, mo)) — the cross-wave
// merge consumes m as the comparison key (round-3 bug).
// ---------------------------------------------------------------------------
__global__ __launch_bounds__(256, 4) void k_main(
    const float* __restrict__ query,
    const float* __restrict__ refp,   // (NLVL, NQ, 2)
    const float* __restrict__ voff,   // (NQ, 8, 4, 2)
    const float* __restrict__ vaw,    // (NQ, 8, 4)
    const __half* __restrict__ vflat, // (NPIX, 128) pixel-major fp16
    const float* __restrict__ gmap,   // (NPIX, 8) per-head fp32 logit map
    const float* __restrict__ Wout,   // (128, 128)
    const float* __restrict__ bout,   // (128)
    float* __restrict__ out0,         // (NQ, 128)
    float* __restrict__ out1) {       // (NQ) argmax level, as float
    const int t = threadIdx.x;
    const int qslot = t >> 7;         // 0..1
    const int w2 = (t >> 6) & 1;      // wave index within query
    const int half = (t >> 5) & 1;
    const int sub = t & 31;
    const int h  = sub >> 2;
    const int c4 = sub & 3;
    const int q = blockIdx.x * 2 + qslot;

    __shared__ float  s_rpy[2][NLVL];
    __shared__ float4 s_acc[2][32];
    __shared__ float  s_z[2], s_m[2];
    __shared__ int    s_b[2];

    // cooperative preload of ref.y for this block's 2 queries
    if (t < 2 * NLVL) {
        const int ql = t / NLVL, l = t - ql * NLVL;
        const int qq = blockIdx.x * 2 + ql;
        s_rpy[ql][l] = refp[((size_t)l * NQ + qq) * 2 + 1];
    }

    const float4* offp = (const float4*)(voff + (size_t)q * 64 + h * 8);
    const float4 o01 = offp[0];       // p0.x p0.y p1.x p1.y
    const float4 o23 = offp[1];
    const float4 awv4 = *(const float4*)(vaw + (size_t)q * 32 + h * 4);
    const float rpx = refp[(size_t)q * 2];   // col is level-invariant
    // lane-fixed 4-channel slot within a 32-slot fp16 pixel record
    const h4v* vbase = (const h4v*)vflat + sub;   // sub == h*4 + c4

    const float offx[4] = {o01.x, o01.z, o23.x, o23.z};
    const float offy[4] = {o01.y, o01.w, o23.y, o23.w};
    const float awv[4]  = {awv4.x, awv4.y, awv4.z, awv4.w};

    // level-independent x-axis state per point (pixel stride = 32 h4v slots)
    float wx0[NPOINTS], wx1[NPOINTS], oyc[NPOINTS];
    int xo0[NPOINTS], xo1[NPOINTS];
#pragma unroll
    for (int p = 0; p < NPOINTS; ++p) {
        const float px = fmaf(rpx, (float)WSP, offx[p]) - 0.5f;
        const float fx = floorf(px);
        const float dx = px - fx;
        const int x0 = (int)fx, x1 = x0 + 1;
        const float a = awv[p];
        wx0[p] = ((unsigned)x0 < (unsigned)WSP) ? a * (1.f - dx) : 0.f;
        wx1[p] = ((unsigned)x1 < (unsigned)WSP) ? a * dx : 0.f;
        xo0[p] = min(max(x0, 0), WSP - 1) * 32;
        xo1[p] = min(max(x1, 0), WSP - 1) * 32;
        oyc[p] = offy[p] - 0.5f;
    }

    // this lane's own (h, p=c4) point: scalar x-state for the fp32 g map
    // (round-3's exact formulation — argmax-proven)
    const float offx_c = (c4 == 0) ? o01.x : (c4 == 1) ? o01.z : (c4 == 2) ? o23.x : o23.z;
    const float offy_c = (c4 == 0) ? o01.y : (c4 == 1) ? o01.w : (c4 == 2) ? o23.y : o23.w;
    const float a_c    = (c4 == 0) ? awv4.x : (c4 == 1) ? awv4.y : (c4 == 2) ? awv4.z : awv4.w;
    const float pxc = fmaf(rpx, (float)WSP, offx_c) - 0.5f;
    const float fxc = floorf(pxc);
    const float dxc = pxc - fxc;
    const int x0c = (int)fxc, x1c = x0c + 1;
    const float gwx0 = ((unsigned)x0c < (unsigned)WSP) ? a_c * (1.f - dxc) : 0.f;
    const float gwx1 = ((unsigned)x1c < (unsigned)WSP) ? a_c * dxc : 0.f;
    const int gx0 = min(max(x0c, 0), WSP - 1) * NHEADS + h;
    const int gx1 = min(max(x1c, 0), WSP - 1) * NHEADS + h;
    const float oyc_c = offy_c - 0.5f;

    __syncthreads();

    float4 acc = {0.f, 0.f, 0.f, 0.f};
    float Z = 0.f, m = -1e30f;
    int best = 0;

#pragma unroll 1
    for (int i = 0; i < 13; ++i) {
        if (4 * i + (w2 << 1) >= NLVL) break;   // wave-uniform (depends on w2 only)
        const int l = 4 * i + (w2 << 1) + half;
        const float rpy = s_rpy[qslot][l];

        // ---- logit gathers for this lane's own point (fp32 g map) ----
        const float pyc = fmaf(rpy, (float)HSP, oyc_c);
        const float fyc = floorf(pyc);
        const float dyc = pyc - fyc;
        const int gy0 = (int)fyc, gy1 = gy0 + 1;
        const float gt0 = ((unsigned)gy0 < (unsigned)HSP) ? (1.f - dyc) : 0.f;
        const float gt1 = ((unsigned)gy1 < (unsigned)HSP) ? dyc : 0.f;
        const int gr0 = min(max(gy0, 0), HSP - 1) * (WSP * NHEADS);
        const int gr1 = min(max(gy1, 0), HSP - 1) * (WSP * NHEADS);
        const float g00 = gmap[gr0 + gx0];
        const float g01 = gmap[gr0 + gx1];
        const float g10 = gmap[gr1 + gx0];
        const float g11 = gmap[gr1 + gx1];

        // ---- stage: issue all 16 corner loads (8 B each), then consume ----
        h4v v00[NPOINTS], v01[NPOINTS], v10[NPOINTS], v11[NPOINTS];
        float w00[NPOINTS], w01[NPOINTS], w10[NPOINTS], w11[NPOINTS];
#pragma unroll
        for (int p = 0; p < NPOINTS; ++p) {
            const float py = fmaf(rpy, (float)HSP, oyc[p]);
            const float fy = floorf(py);
            const float dy = py - fy;
            const int y0 = (int)fy, y1 = y0 + 1;
            const float t0 = ((unsigned)y0 < (unsigned)HSP) ? (1.f - dy) : 0.f;
            const float t1 = ((unsigned)y1 < (unsigned)HSP) ? dy : 0.f;
            const int rb0 = min(max(y0, 0), HSP - 1) * (WSP * 32);
            const int rb1 = min(max(y1, 0), HSP - 1) * (WSP * 32);
            v00[p] = vbase[rb0 + xo0[p]];
            v01[p] = vbase[rb0 + xo1[p]];
            v10[p] = vbase[rb1 + xo0[p]];
            v11[p] = vbase[rb1 + xo1[p]];
            w00[p] = wx0[p] * t0;
            w01[p] = wx1[p] * t0;
            w10[p] = wx0[p] * t1;
            w11[p] = wx1[p] * t1;
        }
        float4 s = {0.f, 0.f, 0.f, 0.f};
#pragma unroll
        for (int p = 0; p < NPOINTS; ++p) {
            const float4 f00 = h4_to_f4(v00[p]);
            const float4 f01 = h4_to_f4(v01[p]);
            const float4 f10 = h4_to_f4(v10[p]);
            const float4 f11 = h4_to_f4(v11[p]);
            s.x = fmaf(w00[p], f00.x, s.x); s.y = fmaf(w00[p], f00.y, s.y);
            s.z = fmaf(w00[p], f00.z, s.z); s.w = fmaf(w00[p], f00.w, s.w);
            s.x = fmaf(w01[p], f01.x, s.x); s.y = fmaf(w01[p], f01.y, s.y);
            s.z = fmaf(w01[p], f01.z, s.z); s.w = fmaf(w01[p], f01.w, s.w);
            s.x = fmaf(w10[p], f10.x, s.x); s.y = fmaf(w10[p], f10.y, s.y);
            s.z = fmaf(w10[p], f10.z, s.z); s.w = fmaf(w10[p], f10.w, s.w);
            s.x = fmaf(w11[p], f11.x, s.x); s.y = fmaf(w11[p], f11.y, s.y);
            s.z = fmaf(w11[p], f11.z, s.z); s.w = fmaf(w11[p], f11.w, s.w);
        }
        // logit from the fp32 g map (round-3 formula), reduced over 32 lanes
        float row0 = gwx0 * g00; row0 = fmaf(gwx1, g01, row0);
        float row1 = gwx0 * g10; row1 = fmaf(gwx1, g11, row1);
        float part = gt0 * row0; part = fmaf(gt1, row1, part);
#pragma unroll
        for (int d = 1; d < 32; d <<= 1)
            part += __shfl_xor(part, d, 64);
        const float e = __expf(part);
        Z += e;
        acc.x = fmaf(e, s.x, acc.x);
        acc.y = fmaf(e, s.y, acc.y);
        acc.z = fmaf(e, s.z, acc.z);
        acc.w = fmaf(e, s.w, acc.w);
        best = (part > m) ? l : best;   // strict > : first occurrence wins
        m = fmaxf(part, m);
    }

    // merge the two halves of this wave (exact: plain sums, no rescale)
    {
        const float mo = __shfl_xor(m, 32, 64);
        const int   bo = __shfl_xor(best, 32, 64);
        const float Zo = __shfl_xor(Z, 32, 64);
        const float ax = __shfl_xor(acc.x, 32, 64);
        const float ay = __shfl_xor(acc.y, 32, 64);
        const float az = __shfl_xor(acc.z, 32, 64);
        const float aw_ = __shfl_xor(acc.w, 32, 64);
        const bool takeOther = (mo > m) || (mo == m && bo < best);
        best = takeOther ? bo : best;
        m = fmaxf(m, mo);               // <- merge the key too (round-3 fix)
        Z += Zo;
        acc.x += ax; acc.y += ay; acc.z += az; acc.w += aw_;
    }

    // wave 1 publishes its partials; wave 0 merges and finishes
    if (w2 == 1) {
        if (half == 0) s_acc[qslot][sub] = acc;
        if ((t & 63) == 0) { s_z[qslot] = Z; s_m[qslot] = m; s_b[qslot] = best; }
    }
    __syncthreads();

    if (w2 == 0) {
        const float4 ao = s_acc[qslot][sub];
        const float Zo = s_z[qslot];
        const float mo = s_m[qslot];
        const int   bo = s_b[qslot];
        const bool takeOther = (mo > m) || (mo == m && bo < best);
        best = takeOther ? bo : best;
        Z += Zo;
        acc.x += ao.x; acc.y += ao.y; acc.z += ao.z; acc.w += ao.w;

        const float inv = 1.f / Z;
        if (half == 0) {
            float4 sv;
            sv.x = acc.x * inv; sv.y = acc.y * inv;
            sv.z = acc.z * inv; sv.w = acc.w * inv;
            s_acc[qslot][sub] = sv;       // channel-group index == sub
            if (sub == 0) out1[q] = (float)best;
        }
        // same-wave DS ordering makes the write visible to both halves below

        // final: out[dp] = sum_c s[c]*Wout[c][dp] + bout[dp] + 2*query[q][dp]
        // split-K across the two halves: half0 sums cg 0..15, half1 cg 16..31
        const int dpb = sub * 4;
        float4 r = {0.f, 0.f, 0.f, 0.f};
        if (half == 0) {
            const float4 b4 = *(const float4*)(bout + dpb);
            const float4 q4 = *(const float4*)(query + (size_t)q * EMBED + dpb);
            r.x = fmaf(2.f, q4.x, b4.x);
            r.y = fmaf(2.f, q4.y, b4.y);
            r.z = fmaf(2.f, q4.z, b4.z);
            r.w = fmaf(2.f, q4.w, b4.w);
        }
        const float4* srow = s_acc[qslot];
        const int cg0 = half * 16;
#pragma unroll 4
        for (int cg = cg0; cg < cg0 + 16; ++cg) {
            const float4 s4 = srow[cg];
            const float4 w0 = *(const float4*)(Wout + (size_t)(cg * 4 + 0) * EMBED + dpb);
            const float4 w1 = *(const float4*)(Wout + (size_t)(cg * 4 + 1) * EMBED + dpb);
            const float4 w2v = *(const float4*)(Wout + (size_t)(cg * 4 + 2) * EMBED + dpb);
            const float4 w3 = *(const float4*)(Wout + (size_t)(cg * 4 + 3) * EMBED + dpb);
            r.x = fmaf(s4.x, w0.x, r.x); r.y = fmaf(s4.x, w0.y, r.y);
            r.z = fmaf(s4.x, w0.z, r.z); r.w = fmaf(s4.x, w0.w, r.w);
            r.x = fmaf(s4.y, w1.x, r.x); r.y = fmaf(s4.y, w1.y, r.y);
            r.z = fmaf(s4.y, w1.z, r.z); r.w = fmaf(s4.y, w1.w, r.w);
            r.x = fmaf(s4.z, w2v.x, r.x); r.y = fmaf(s4.z, w2v.y, r.y);
            r.z = fmaf(s4.z, w2v.z, r.z); r.w = fmaf(s4.z, w2v.w, r.w);
            r.x = fmaf(s4.w, w3.x, r.x); r.y = fmaf(s4.w, w3.y, r.y);
            r.z = fmaf(s4.w, w3.z, r.z); r.w = fmaf(s4.w, w3.w, r.w);
        }
        // combine the two half-sums and store from half 0
        {
            const float rx = __shfl_xor(r.x, 32, 64);
            const float ry = __shfl_xor(r.y, 32, 64);
            const float rz = __shfl_xor(r.z, 32, 64);
            const float rw = __shfl_xor(r.w, 32, 64);
            r.x += rx; r.y += ry; r.z += rz; r.w += rw;
        }
        if (half == 0)
            *(float4*)(out0 + (size_t)q * EMBED + dpb) = r;
    }
}

// ---------------------------------------------------------------------------
extern "C" void kernel_launch(void* const* d_in, const int* in_sizes, int n_in,
                              void* d_out, int out_size, void* d_ws, size_t ws_size,
                              hipStream_t stream) {
    const float* query = (const float*)d_in[0];
    const float* value = (const float*)d_in[1];
    const float* refp  = (const float*)d_in[2];
    const float* Woff  = (const float*)d_in[3];
    const float* boff  = (const float*)d_in[4];
    const float* Wattn = (const float*)d_in[5];
    const float* battn = (const float*)d_in[6];
    const float* Wval  = (const float*)d_in[7];
    const float* bval  = (const float*)d_in[8];
    const float* Wout  = (const float*)d_in[9];
    const float* bout  = (const float*)d_in[10];
    const float* Wproj = (const float*)d_in[11];
    // d_in[12] = b_proj: level-constant -> cancels in softmax/argmax, unused.

    float* ws = (float*)d_ws;
    __half* ws_v = (__half*)ws;                           // NPIX*128 halves
    float* ws_g   = ws + (size_t)NPIX * EMBED / 2;        // NPIX*8 fp32
    float* ws_off = ws_g + (size_t)NPIX * NHEADS;         // NQ*64
    float* ws_aw  = ws_off + (size_t)NQ * 64;             // NQ*32

    float* out0 = (float*)d_out;
    float* out1 = out0 + (size_t)NQ * EMBED;

    hipLaunchKernelGGL(k_prep, dim3(GRID_A + GRID_B), dim3(256), 0, stream,
                       value, Wval, bval, query, Woff, boff, Wattn, battn,
                       Wout, Wproj, ws_v, ws_g, ws_off, ws_aw);
    hipLaunchKernelGGL(k_main, dim3(NQ / 2), dim3(256), 0, stream,
                       query, refp, ws_off, ws_aw, ws_v, ws_g, Wout, bout,
                       out0, out1);
}

// Round 6
// 263.385 us; speedup vs baseline: 1.1113x; 1.0869x over previous
//
#include <hip/hip_runtime.h>
#include <math.h>

#define EMBED   128
#define NHEADS  8
#define NPOINTS 4
#define HD      16
#define HSP     51
#define WSP     102
#define NPIX    (HSP * WSP)   // 5202
#define NQ      10000
#define NLVL    50

// Zero-padded pixel-major value map: rows -1..52 (54), cols -1..103 (105).
// Valid source pixel (y,x) lives at map slot (y+1, x+1). Border slots are
// zero-filled, so out-of-range bilinear corners contribute exact +0 without
// any validity masks in the inner loop.
#define PROW 54
#define PCOL 105
#define NSLOT (PROW * PCOL)        // 5670
#define ROWQ  (PCOL * 32)          // row stride in float4 units = 3360

// ---------------------------------------------------------------------------
// Fused prep kernel.
//   blocks [0, 709)        : padded value map (8 map-slots/block; border -> 0)
//   blocks [709, 709+1250) : offsets + attention, 8 queries/block
//   last block             : u = W_out @ W_proj
// FMA order per output column unchanged (init bias, ascending k) -> valid
// pixels bitwise-identical to round 2.
// ---------------------------------------------------------------------------
#define GRID_A ((NSLOT + 7) / 8)   // 709
#define GRID_B (NQ / 8)            // 1250

__global__ __launch_bounds__(256) void k_prep(
    const float* __restrict__ value,
    const float* __restrict__ Wv,
    const float* __restrict__ bv,
    const float* __restrict__ query,
    const float* __restrict__ Woff,
    const float* __restrict__ boff,
    const float* __restrict__ Wattn,
    const float* __restrict__ battn,
    const float* __restrict__ Wout,
    const float* __restrict__ Wproj,
    float* __restrict__ vout,     // (PROW*PCOL, 128) padded pixel-major
    float* __restrict__ off_out,
    float* __restrict__ aw_out,
    float* __restrict__ u_out) {
    const int b = blockIdx.x;
    const int t = threadIdx.x;
    __shared__ float srow[8][EMBED];   // 4 KB: value rows or query rows

    if (b < GRID_A) {  // ---- padded value map ----
        const int p    = t >> 5;       // slot index within block 0..7
        const int s    = t & 31;       // column group (4 cols each)
        const int slot = b * 8 + p;
        const int prow = slot / PCOL;
        const int pcol = slot - prow * PCOL;
        const bool inb   = slot < NSLOT;
        const bool valid = inb && prow >= 1 && prow <= HSP
                               && pcol >= 1 && pcol <= WSP;
        const int pix = (prow - 1) * WSP + (pcol - 1);
        if (valid)
            *(float4*)&srow[p][s * 4] =
                *(const float4*)(value + (size_t)pix * EMBED + s * 4);
        __syncthreads();
        float4 acc = {0.f, 0.f, 0.f, 0.f};
        if (valid) {
            acc = *(const float4*)(bv + s * 4);
            const float* vr = srow[p];
            const float* wp = Wv + s * 4;
#pragma unroll 8
            for (int k = 0; k < EMBED; ++k) {
                const float qv = vr[k];
                const float4 w4 = *(const float4*)(wp + (size_t)k * EMBED);
                acc.x = fmaf(qv, w4.x, acc.x);
                acc.y = fmaf(qv, w4.y, acc.y);
                acc.z = fmaf(qv, w4.z, acc.z);
                acc.w = fmaf(qv, w4.w, acc.w);
            }
        }
        if (inb)
            *(float4*)(vout + (size_t)slot * EMBED + s * 4) = acc;
    } else if (b < GRID_A + GRID_B) {  // ---- offsets + attention ----
        const int qi = t >> 5;         // query slot 0..7
        const int s  = t & 31;
        const int q  = (b - GRID_A) * 8 + qi;
        *(float4*)&srow[qi][s * 4] =
            *(const float4*)(query + (size_t)q * EMBED + s * 4);
        __syncthreads();
        if (s < 24) {                  // lanes 0-15: offsets, 16-23: attn
            const float* vr = srow[qi];
            const float* wp;
            int wstride;
            float4 acc;
            if (s < 16) {
                wp = Woff + s * 4; wstride = 64;
                acc = *(const float4*)(boff + s * 4);
            } else {
                wp = Wattn + (s - 16) * 4; wstride = 32;
                acc = *(const float4*)(battn + (s - 16) * 4);
            }
#pragma unroll 8
            for (int k = 0; k < EMBED; ++k) {
                const float qv = vr[k];
                const float4 w4 = *(const float4*)(wp + (size_t)k * wstride);
                acc.x = fmaf(qv, w4.x, acc.x);
                acc.y = fmaf(qv, w4.y, acc.y);
                acc.z = fmaf(qv, w4.z, acc.z);
                acc.w = fmaf(qv, w4.w, acc.w);
            }
            if (s < 16) {
                *(float4*)(off_out + (size_t)q * 64 + s * 4) = acc;
            } else {
                const float mx = fmaxf(fmaxf(acc.x, acc.y), fmaxf(acc.z, acc.w));
                const float e0 = __expf(acc.x - mx), e1 = __expf(acc.y - mx);
                const float e2 = __expf(acc.z - mx), e3 = __expf(acc.w - mx);
                const float inv = 1.f / (e0 + e1 + e2 + e3);
                float4 r;
                r.x = e0 * inv; r.y = e1 * inv; r.z = e2 * inv; r.w = e3 * inv;
                *(float4*)(aw_out + (size_t)q * 32 + (s - 16) * 4) = r;
            }
        }
    } else {  // ---- u = W_out @ W_proj (1 block) ----
        if (t < EMBED) {
            float acc = 0.f;
#pragma unroll 8
            for (int d = 0; d < EMBED; ++d)
                acc = fmaf(Wout[(size_t)t * EMBED + d], Wproj[d], acc);
            u_out[t] = acc;
        }
    }
}

// ---------------------------------------------------------------------------
// Main kernel. Round-2 structure (fused gather + u-dot logit + online
// softmax — proven fastest and argmax-correct), with the bounds math removed:
// the padded-zero map turns every validity mask into an exact +0 product.
// Per point per iter: 1 fma + 1 med3 + floor + cvt + 2 sub + mad + add for
// addressing (was ~19 ops with cndmasks/min/max). Outputs bitwise-identical
// to round 2 (OOB contributions are +0 either way).
// NOTE: the half-merge MUST also merge m (m = fmaxf(m, mo)) — the cross-wave
// merge consumes m as the comparison key (round-3 bug).
// ---------------------------------------------------------------------------
__global__ __launch_bounds__(256, 8) void k_main(
    const float* __restrict__ query,
    const float* __restrict__ refp,   // (NLVL, NQ, 2)
    const float* __restrict__ voff,   // (NQ, 8, 4, 2)
    const float* __restrict__ vaw,    // (NQ, 8, 4)
    const float* __restrict__ vflat,  // (PROW*PCOL, 128) padded pixel-major
    const float* __restrict__ uvec,   // (128)
    const float* __restrict__ Wout,   // (128, 128)
    const float* __restrict__ bout,   // (128)
    float* __restrict__ out0,         // (NQ, 128)
    float* __restrict__ out1) {       // (NQ) argmax level, as float
    const int t = threadIdx.x;
    const int qslot = t >> 7;         // 0..1
    const int w2 = (t >> 6) & 1;      // wave index within query
    const int half = (t >> 5) & 1;
    const int sub = t & 31;
    const int h  = sub >> 2;
    const int c4 = sub & 3;
    const int q = blockIdx.x * 2 + qslot;

    __shared__ float  s_rpy[2][NLVL];
    __shared__ float4 s_acc[2][32];
    __shared__ float  s_z[2], s_m[2];
    __shared__ int    s_b[2];

    // cooperative preload of ref.y for this block's 2 queries
    if (t < 2 * NLVL) {
        const int ql = t / NLVL, l = t - ql * NLVL;
        const int qq = blockIdx.x * 2 + ql;
        s_rpy[ql][l] = refp[((size_t)l * NQ + qq) * 2 + 1];
    }

    const float4* offp = (const float4*)(voff + (size_t)q * 64 + h * 8);
    const float4 o01 = offp[0];       // p0.x p0.y p1.x p1.y
    const float4 o23 = offp[1];
    const float4 awv4 = *(const float4*)(vaw + (size_t)q * 32 + h * 4);
    const float4 u4 = *(const float4*)(uvec + h * 16 + c4 * 4);
    const float rpx = refp[(size_t)q * 2];   // col is level-invariant
    // lane-fixed channel slot within a 32-float4 pixel record
    const float4* vbase = (const float4*)vflat + sub;   // sub == h*4 + c4

    const float offx[4] = {o01.x, o01.z, o23.x, o23.z};
    const float offy[4] = {o01.y, o01.w, o23.y, o23.w};
    const float awv[4]  = {awv4.x, awv4.y, awv4.z, awv4.w};

    // level-independent x-axis state per point (padded map, no masks)
    float wx0[NPOINTS], wx1[NPOINTS], oyc[NPOINTS];
    int xo0[NPOINTS], xo1[NPOINTS];
#pragma unroll
    for (int p = 0; p < NPOINTS; ++p) {
        const float px = fmaf(rpx, (float)WSP, offx[p]) - 0.5f;
        const float pxc = __builtin_amdgcn_fmed3f(px, -1.f, (float)WSP);
        const float fx = floorf(pxc);
        const float dx = pxc - fx;
        const int x0 = (int)fx;
        const float a = awv[p];
        wx0[p] = a * (1.f - dx);
        wx1[p] = a * dx;
        xo0[p] = (x0 + 1) * 32;
        xo1[p] = xo0[p] + 32;
        oyc[p] = offy[p] - 0.5f;
    }

    __syncthreads();

    float4 acc = {0.f, 0.f, 0.f, 0.f};
    float Z = 0.f, m = -1e30f;
    int best = 0;

#pragma unroll 1
    for (int i = 0; i < 13; ++i) {
        if (4 * i + (w2 << 1) >= NLVL) break;   // wave-uniform (depends on w2 only)
        const int l = 4 * i + (w2 << 1) + half;
        const float rpy = s_rpy[qslot][l];

        // ---- stage: issue all 16 corner loads, then consume ----
        float4 v00[NPOINTS], v01[NPOINTS], v10[NPOINTS], v11[NPOINTS];
        float w00[NPOINTS], w01[NPOINTS], w10[NPOINTS], w11[NPOINTS];
#pragma unroll
        for (int p = 0; p < NPOINTS; ++p) {
            const float py = fmaf(rpy, (float)HSP, oyc[p]);
            const float pyc = __builtin_amdgcn_fmed3f(py, -1.f, (float)HSP);
            const float fy = floorf(pyc);
            const float dy = pyc - fy;
            const int y0 = (int)fy;
            const int rb0 = (y0 + 1) * ROWQ;
            const int rb1 = rb0 + ROWQ;
            const float t0 = 1.f - dy;
            v00[p] = vbase[rb0 + xo0[p]];
            v01[p] = vbase[rb0 + xo1[p]];
            v10[p] = vbase[rb1 + xo0[p]];
            v11[p] = vbase[rb1 + xo1[p]];
            w00[p] = wx0[p] * t0;
            w01[p] = wx1[p] * t0;
            w10[p] = wx0[p] * dy;
            w11[p] = wx1[p] * dy;
        }
        float4 s = {0.f, 0.f, 0.f, 0.f};
#pragma unroll
        for (int p = 0; p < NPOINTS; ++p) {
            s.x = fmaf(w00[p], v00[p].x, s.x); s.y = fmaf(w00[p], v00[p].y, s.y);
            s.z = fmaf(w00[p], v00[p].z, s.z); s.w = fmaf(w00[p], v00[p].w, s.w);
            s.x = fmaf(w01[p], v01[p].x, s.x); s.y = fmaf(w01[p], v01[p].y, s.y);
            s.z = fmaf(w01[p], v01[p].z, s.z); s.w = fmaf(w01[p], v01[p].w, s.w);
            s.x = fmaf(w10[p], v10[p].x, s.x); s.y = fmaf(w10[p], v10[p].y, s.y);
            s.z = fmaf(w10[p], v10[p].z, s.z); s.w = fmaf(w10[p], v10[p].w, s.w);
            s.x = fmaf(w11[p], v11[p].x, s.x); s.y = fmaf(w11[p], v11[p].y, s.y);
            s.z = fmaf(w11[p], v11[p].z, s.z); s.w = fmaf(w11[p], v11[p].w, s.w);
        }
        // logit = samp_agg . u, reduced over the 32 lanes of this half
        float part = s.x * u4.x;
        part = fmaf(s.y, u4.y, part);
        part = fmaf(s.z, u4.z, part);
        part = fmaf(s.w, u4.w, part);
#pragma unroll
        for (int d = 1; d < 32; d <<= 1)
            part += __shfl_xor(part, d, 64);
        const float e = __expf(part);
        Z += e;
        acc.x = fmaf(e, s.x, acc.x);
        acc.y = fmaf(e, s.y, acc.y);
        acc.z = fmaf(e, s.z, acc.z);
        acc.w = fmaf(e, s.w, acc.w);
        best = (part > m) ? l : best;   // strict > : first occurrence wins
        m = fmaxf(part, m);
    }

    // merge the two halves of this wave (exact: plain sums, no rescale)
    {
        const float mo = __shfl_xor(m, 32, 64);
        const int   bo = __shfl_xor(best, 32, 64);
        const float Zo = __shfl_xor(Z, 32, 64);
        const float ax = __shfl_xor(acc.x, 32, 64);
        const float ay = __shfl_xor(acc.y, 32, 64);
        const float az = __shfl_xor(acc.z, 32, 64);
        const float aw_ = __shfl_xor(acc.w, 32, 64);
        const bool takeOther = (mo > m) || (mo == m && bo < best);
        best = takeOther ? bo : best;
        m = fmaxf(m, mo);               // <- merge the key too (round-3 fix)
        Z += Zo;
        acc.x += ax; acc.y += ay; acc.z += az; acc.w += aw_;
    }

    // wave 1 publishes its partials; wave 0 merges and finishes
    if (w2 == 1) {
        if (half == 0) s_acc[qslot][sub] = acc;
        if ((t & 63) == 0) { s_z[qslot] = Z; s_m[qslot] = m; s_b[qslot] = best; }
    }
    __syncthreads();

    if (w2 == 0) {
        const float4 ao = s_acc[qslot][sub];
        const float Zo = s_z[qslot];
        const float mo = s_m[qslot];
        const int   bo = s_b[qslot];
        const bool takeOther = (mo > m) || (mo == m && bo < best);
        best = takeOther ? bo : best;
        Z += Zo;
        acc.x += ao.x; acc.y += ao.y; acc.z += ao.z; acc.w += ao.w;

        const float inv = 1.f / Z;
        if (half == 0) {
            float4 sv;
            sv.x = acc.x * inv; sv.y = acc.y * inv;
            sv.z = acc.z * inv; sv.w = acc.w * inv;
            s_acc[qslot][sub] = sv;       // channel-group index == sub
            if (sub == 0) out1[q] = (float)best;
        }
        // same-wave DS ordering makes the write visible to both halves below

        // final: out[dp] = sum_c s[c]*Wout[c][dp] + bout[dp] + 2*query[q][dp]
        // split-K across the two halves: half0 sums cg 0..15, half1 cg 16..31
        const int dpb = sub * 4;
        float4 r = {0.f, 0.f, 0.f, 0.f};
        if (half == 0) {
            const float4 b4 = *(const float4*)(bout + dpb);
            const float4 q4 = *(const float4*)(query + (size_t)q * EMBED + dpb);
            r.x = fmaf(2.f, q4.x, b4.x);
            r.y = fmaf(2.f, q4.y, b4.y);
            r.z = fmaf(2.f, q4.z, b4.z);
            r.w = fmaf(2.f, q4.w, b4.w);
        }
        const float4* srow = s_acc[qslot];
        const int cg0 = half * 16;
#pragma unroll 4
        for (int cg = cg0; cg < cg0 + 16; ++cg) {
            const float4 s4 = srow[cg];
            const float4 w0 = *(const float4*)(Wout + (size_t)(cg * 4 + 0) * EMBED + dpb);
            const float4 w1 = *(const float4*)(Wout + (size_t)(cg * 4 + 1) * EMBED + dpb);
            const float4 w2v = *(const float4*)(Wout + (size_t)(cg * 4 + 2) * EMBED + dpb);
            const float4 w3 = *(const float4*)(Wout + (size_t)(cg * 4 + 3) * EMBED + dpb);
            r.x = fmaf(s4.x, w0.x, r.x); r.y = fmaf(s4.x, w0.y, r.y);
            r.z = fmaf(s4.x, w0.z, r.z); r.w = fmaf(s4.x, w0.w, r.w);
            r.x = fmaf(s4.y, w1.x, r.x); r.y = fmaf(s4.y, w1.y, r.y);
            r.z = fmaf(s4.y, w1.z, r.z); r.w = fmaf(s4.y, w1.w, r.w);
            r.x = fmaf(s4.z, w2v.x, r.x); r.y = fmaf(s4.z, w2v.y, r.y);
            r.z = fmaf(s4.z, w2v.z, r.z); r.w = fmaf(s4.z, w2v.w, r.w);
            r.x = fmaf(s4.w, w3.x, r.x); r.y = fmaf(s4.w, w3.y, r.y);
            r.z = fmaf(s4.w, w3.z, r.z); r.w = fmaf(s4.w, w3.w, r.w);
        }
        // combine the two half-sums and store from half 0
        {
            const float rx = __shfl_xor(r.x, 32, 64);
            const float ry = __shfl_xor(r.y, 32, 64);
            const float rz = __shfl_xor(r.z, 32, 64);
            const float rw = __shfl_xor(r.w, 32, 64);
            r.x += rx; r.y += ry; r.z += rz; r.w += rw;
        }
        if (half == 0)
            *(float4*)(out0 + (size_t)q * EMBED + dpb) = r;
    }
}

// ---------------------------------------------------------------------------
extern "C" void kernel_launch(void* const* d_in, const int* in_sizes, int n_in,
                              void* d_out, int out_size, void* d_ws, size_t ws_size,
                              hipStream_t stream) {
    const float* query = (const float*)d_in[0];
    const float* value = (const float*)d_in[1];
    const float* refp  = (const float*)d_in[2];
    const float* Woff  = (const float*)d_in[3];
    const float* boff  = (const float*)d_in[4];
    const float* Wattn = (const float*)d_in[5];
    const float* battn = (const float*)d_in[6];
    const float* Wval  = (const float*)d_in[7];
    const float* bval  = (const float*)d_in[8];
    const float* Wout  = (const float*)d_in[9];
    const float* bout  = (const float*)d_in[10];
    const float* Wproj = (const float*)d_in[11];
    // d_in[12] = b_proj: level-constant -> cancels in softmax/argmax, unused.

    float* ws = (float*)d_ws;
    float* ws_v   = ws;                                   // NSLOT*128 padded map
    float* ws_off = ws_v + (size_t)NSLOT * EMBED;         // NQ*64
    float* ws_aw  = ws_off + (size_t)NQ * 64;             // NQ*32
    float* ws_u   = ws_aw + (size_t)NQ * 32;              // 128

    float* out0 = (float*)d_out;
    float* out1 = out0 + (size_t)NQ * EMBED;

    hipLaunchKernelGGL(k_prep, dim3(GRID_A + GRID_B + 1), dim3(256), 0, stream,
                       value, Wval, bval, query, Woff, boff, Wattn, battn,
                       Wout, Wproj, ws_v, ws_off, ws_aw, ws_u);
    hipLaunchKernelGGL(k_main, dim3(NQ / 2), dim3(256), 0, stream,
                       query, refp, ws_off, ws_aw, ws_v, ws_u, Wout, bout,
                       out0, out1);
}

// Round 7
// 250.894 us; speedup vs baseline: 1.1666x; 1.0498x over previous
//
#include <hip/hip_runtime.h>
#include <math.h>

#define EMBED   128
#define NHEADS  8
#define NPOINTS 4
#define HD      16
#define HSP     51
#define WSP     102
#define NPIX    (HSP * WSP)   // 5202
#define NQ      10000
#define NLVL    50

// Zero-padded pixel-major value map: rows -1..52 (54), cols -1..103 (105).
// Valid source pixel (y,x) lives at map slot (y+1, x+1). Border slots are
// zero-filled, so out-of-range bilinear corners contribute exact +0 without
// any validity masks in the inner loop.
#define PROW 54
#define PCOL 105
#define NSLOT (PROW * PCOL)        // 5670
#define ROWQ  (PCOL * 32)          // row stride in float4 units = 3360

// ---------------------------------------------------------------------------
// Fused prep kernel (identical to round 6 — verified).
//   blocks [0, 709)        : padded value map (8 map-slots/block; border -> 0)
//   blocks [709, 709+1250) : offsets + attention, 8 queries/block
//   last block             : u = W_out @ W_proj
// ---------------------------------------------------------------------------
#define GRID_A ((NSLOT + 7) / 8)   // 709
#define GRID_B (NQ / 8)            // 1250

__global__ __launch_bounds__(256) void k_prep(
    const float* __restrict__ value,
    const float* __restrict__ Wv,
    const float* __restrict__ bv,
    const float* __restrict__ query,
    const float* __restrict__ Woff,
    const float* __restrict__ boff,
    const float* __restrict__ Wattn,
    const float* __restrict__ battn,
    const float* __restrict__ Wout,
    const float* __restrict__ Wproj,
    float* __restrict__ vout,     // (PROW*PCOL, 128) padded pixel-major
    float* __restrict__ off_out,
    float* __restrict__ aw_out,
    float* __restrict__ u_out) {
    const int b = blockIdx.x;
    const int t = threadIdx.x;
    __shared__ float srow[8][EMBED];   // 4 KB: value rows or query rows

    if (b < GRID_A) {  // ---- padded value map ----
        const int p    = t >> 5;       // slot index within block 0..7
        const int s    = t & 31;       // column group (4 cols each)
        const int slot = b * 8 + p;
        const int prow = slot / PCOL;
        const int pcol = slot - prow * PCOL;
        const bool inb   = slot < NSLOT;
        const bool valid = inb && prow >= 1 && prow <= HSP
                               && pcol >= 1 && pcol <= WSP;
        const int pix = (prow - 1) * WSP + (pcol - 1);
        if (valid)
            *(float4*)&srow[p][s * 4] =
                *(const float4*)(value + (size_t)pix * EMBED + s * 4);
        __syncthreads();
        float4 acc = {0.f, 0.f, 0.f, 0.f};
        if (valid) {
            acc = *(const float4*)(bv + s * 4);
            const float* vr = srow[p];
            const float* wp = Wv + s * 4;
#pragma unroll 8
            for (int k = 0; k < EMBED; ++k) {
                const float qv = vr[k];
                const float4 w4 = *(const float4*)(wp + (size_t)k * EMBED);
                acc.x = fmaf(qv, w4.x, acc.x);
                acc.y = fmaf(qv, w4.y, acc.y);
                acc.z = fmaf(qv, w4.z, acc.z);
                acc.w = fmaf(qv, w4.w, acc.w);
            }
        }
        if (inb)
            *(float4*)(vout + (size_t)slot * EMBED + s * 4) = acc;
    } else if (b < GRID_A + GRID_B) {  // ---- offsets + attention ----
        const int qi = t >> 5;         // query slot 0..7
        const int s  = t & 31;
        const int q  = (b - GRID_A) * 8 + qi;
        *(float4*)&srow[qi][s * 4] =
            *(const float4*)(query + (size_t)q * EMBED + s * 4);
        __syncthreads();
        if (s < 24) {                  // lanes 0-15: offsets, 16-23: attn
            const float* vr = srow[qi];
            const float* wp;
            int wstride;
            float4 acc;
            if (s < 16) {
                wp = Woff + s * 4; wstride = 64;
                acc = *(const float4*)(boff + s * 4);
            } else {
                wp = Wattn + (s - 16) * 4; wstride = 32;
                acc = *(const float4*)(battn + (s - 16) * 4);
            }
#pragma unroll 8
            for (int k = 0; k < EMBED; ++k) {
                const float qv = vr[k];
                const float4 w4 = *(const float4*)(wp + (size_t)k * wstride);
                acc.x = fmaf(qv, w4.x, acc.x);
                acc.y = fmaf(qv, w4.y, acc.y);
                acc.z = fmaf(qv, w4.z, acc.z);
                acc.w = fmaf(qv, w4.w, acc.w);
            }
            if (s < 16) {
                *(float4*)(off_out + (size_t)q * 64 + s * 4) = acc;
            } else {
                const float mx = fmaxf(fmaxf(acc.x, acc.y), fmaxf(acc.z, acc.w));
                const float e0 = __expf(acc.x - mx), e1 = __expf(acc.y - mx);
                const float e2 = __expf(acc.z - mx), e3 = __expf(acc.w - mx);
                const float inv = 1.f / (e0 + e1 + e2 + e3);
                float4 r;
                r.x = e0 * inv; r.y = e1 * inv; r.z = e2 * inv; r.w = e3 * inv;
                *(float4*)(aw_out + (size_t)q * 32 + (s - 16) * 4) = r;
            }
        }
    } else {  // ---- u = W_out @ W_proj (1 block) ----
        if (t < EMBED) {
            float acc = 0.f;
#pragma unroll 8
            for (int d = 0; d < EMBED; ++d)
                acc = fmaf(Wout[(size_t)t * EMBED + d], Wproj[d], acc);
            u_out[t] = acc;
        }
    }
}

// ---------------------------------------------------------------------------
// Main kernel. Round-9 = round-6's padded-map addressing + the two fixes:
//  * __launch_bounds__(256, 4): round-6's (256,8) squeezed VGPR to 32, which
//    made the 16-load stage impossible (needs 64 VGPRs) -> loads serialized.
//    Occupancy 76% did NOT help (ILP-bound, not wave-bound). Give the
//    allocator ~128 VGPR so all 16 corner loads stay in flight.
//  * 32-bit index + UNIFORM base pointer: per-lane 64-bit address adds are
//    gone (hardware does s[base]+voffset); the x-neighbor (+32 float4s =
//    512 B) is a visible constant -> folds into the load immediate offset;
//    sub and the +1 row/col pad shifts are pre-folded into xa[p].
// Outputs bitwise-identical to rounds 2/6 (same corners, weights, order).
// NOTE: the half-merge MUST also merge m (m = fmaxf(m, mo)) — the cross-wave
// merge consumes m as the comparison key (round-3 bug).
// ---------------------------------------------------------------------------
__global__ __launch_bounds__(256, 4) void k_main(
    const float* __restrict__ query,
    const float* __restrict__ refp,   // (NLVL, NQ, 2)
    const float* __restrict__ voff,   // (NQ, 8, 4, 2)
    const float* __restrict__ vaw,    // (NQ, 8, 4)
    const float* __restrict__ vflat,  // (PROW*PCOL, 128) padded pixel-major
    const float* __restrict__ uvec,   // (128)
    const float* __restrict__ Wout,   // (128, 128)
    const float* __restrict__ bout,   // (128)
    float* __restrict__ out0,         // (NQ, 128)
    float* __restrict__ out1) {       // (NQ) argmax level, as float
    const int t = threadIdx.x;
    const int qslot = t >> 7;         // 0..1
    const int w2 = (t >> 6) & 1;      // wave index within query
    const int half = (t >> 5) & 1;
    const int sub = t & 31;
    const int h  = sub >> 2;
    const int c4 = sub & 3;
    const int q = blockIdx.x * 2 + qslot;

    __shared__ float  s_rpy[2][NLVL];
    __shared__ float4 s_acc[2][32];
    __shared__ float  s_z[2], s_m[2];
    __shared__ int    s_b[2];

    // cooperative preload of ref.y for this block's 2 queries
    if (t < 2 * NLVL) {
        const int ql = t / NLVL, l = t - ql * NLVL;
        const int qq = blockIdx.x * 2 + ql;
        s_rpy[ql][l] = refp[((size_t)l * NQ + qq) * 2 + 1];
    }

    const float4* offp = (const float4*)(voff + (size_t)q * 64 + h * 8);
    const float4 o01 = offp[0];       // p0.x p0.y p1.x p1.y
    const float4 o23 = offp[1];
    const float4 awv4 = *(const float4*)(vaw + (size_t)q * 32 + h * 4);
    const float4 u4 = *(const float4*)(uvec + h * 16 + c4 * 4);
    const float rpx = refp[(size_t)q * 2];   // col is level-invariant
    const float4* vflat4 = (const float4*)vflat;   // UNIFORM base (SGPR pair)

    const float offx[4] = {o01.x, o01.z, o23.x, o23.z};
    const float offy[4] = {o01.y, o01.w, o23.y, o23.w};
    const float awv[4]  = {awv4.x, awv4.y, awv4.z, awv4.w};

    // level-independent x-axis state per point. xa[p] pre-folds:
    //   (x0+1)*32  (col pad shift), +ROWQ (row pad shift), +sub (lane slot)
    float wx0[NPOINTS], wx1[NPOINTS], oyc[NPOINTS];
    int xa[NPOINTS];
#pragma unroll
    for (int p = 0; p < NPOINTS; ++p) {
        const float px = fmaf(rpx, (float)WSP, offx[p]) - 0.5f;
        const float pxc = __builtin_amdgcn_fmed3f(px, -1.f, (float)WSP);
        const float fx = floorf(pxc);
        const float dx = pxc - fx;
        const int x0 = (int)fx;
        const float a = awv[p];
        wx0[p] = a * (1.f - dx);
        wx1[p] = a * dx;
        xa[p] = (x0 + 1) * 32 + ROWQ + sub;
        oyc[p] = offy[p] - 0.5f;
    }

    __syncthreads();

    float4 acc = {0.f, 0.f, 0.f, 0.f};
    float Z = 0.f, m = -1e30f;
    int best = 0;

#pragma unroll 1
    for (int i = 0; i < 13; ++i) {
        if (4 * i + (w2 << 1) >= NLVL) break;   // wave-uniform (depends on w2 only)
        const int l = 4 * i + (w2 << 1) + half;
        const float rpy = s_rpy[qslot][l];

        // ---- stage: issue all 16 corner loads, then consume ----
        float4 v00[NPOINTS], v01[NPOINTS], v10[NPOINTS], v11[NPOINTS];
        float w00[NPOINTS], w01[NPOINTS], w10[NPOINTS], w11[NPOINTS];
#pragma unroll
        for (int p = 0; p < NPOINTS; ++p) {
            const float py = fmaf(rpy, (float)HSP, oyc[p]);
            const float pyc = __builtin_amdgcn_fmed3f(py, -1.f, (float)HSP);
            const float fy = floorf(pyc);
            const float dy = pyc - fy;
            const int y0 = (int)fy;
            const int i0 = y0 * ROWQ + xa[p];   // map row y0+1 (pad folded in)
            const int i1 = i0 + ROWQ;           // map row y0+2
            const float t0 = 1.f - dy;
            v00[p] = vflat4[i0];
            v01[p] = vflat4[i0 + 32];           // +512 B -> imm offset fold
            v10[p] = vflat4[i1];
            v11[p] = vflat4[i1 + 32];
            w00[p] = wx0[p] * t0;
            w01[p] = wx1[p] * t0;
            w10[p] = wx0[p] * dy;
            w11[p] = wx1[p] * dy;
        }
        float4 s = {0.f, 0.f, 0.f, 0.f};
#pragma unroll
        for (int p = 0; p < NPOINTS; ++p) {
            s.x = fmaf(w00[p], v00[p].x, s.x); s.y = fmaf(w00[p], v00[p].y, s.y);
            s.z = fmaf(w00[p], v00[p].z, s.z); s.w = fmaf(w00[p], v00[p].w, s.w);
            s.x = fmaf(w01[p], v01[p].x, s.x); s.y = fmaf(w01[p], v01[p].y, s.y);
            s.z = fmaf(w01[p], v01[p].z, s.z); s.w = fmaf(w01[p], v01[p].w, s.w);
            s.x = fmaf(w10[p], v10[p].x, s.x); s.y = fmaf(w10[p], v10[p].y, s.y);
            s.z = fmaf(w10[p], v10[p].z, s.z); s.w = fmaf(w10[p], v10[p].w, s.w);
            s.x = fmaf(w11[p], v11[p].x, s.x); s.y = fmaf(w11[p], v11[p].y, s.y);
            s.z = fmaf(w11[p], v11[p].z, s.z); s.w = fmaf(w11[p], v11[p].w, s.w);
        }
        // logit = samp_agg . u, reduced over the 32 lanes of this half
        float part = s.x * u4.x;
        part = fmaf(s.y, u4.y, part);
        part = fmaf(s.z, u4.z, part);
        part = fmaf(s.w, u4.w, part);
#pragma unroll
        for (int d = 1; d < 32; d <<= 1)
            part += __shfl_xor(part, d, 64);
        const float e = __expf(part);
        Z += e;
        acc.x = fmaf(e, s.x, acc.x);
        acc.y = fmaf(e, s.y, acc.y);
        acc.z = fmaf(e, s.z, acc.z);
        acc.w = fmaf(e, s.w, acc.w);
        best = (part > m) ? l : best;   // strict > : first occurrence wins
        m = fmaxf(part, m);
    }

    // merge the two halves of this wave (exact: plain sums, no rescale)
    {
        const float mo = __shfl_xor(m, 32, 64);
        const int   bo = __shfl_xor(best, 32, 64);
        const float Zo = __shfl_xor(Z, 32, 64);
        const float ax = __shfl_xor(acc.x, 32, 64);
        const float ay = __shfl_xor(acc.y, 32, 64);
        const float az = __shfl_xor(acc.z, 32, 64);
        const float aw_ = __shfl_xor(acc.w, 32, 64);
        const bool takeOther = (mo > m) || (mo == m && bo < best);
        best = takeOther ? bo : best;
        m = fmaxf(m, mo);               // <- merge the key too (round-3 fix)
        Z += Zo;
        acc.x += ax; acc.y += ay; acc.z += az; acc.w += aw_;
    }

    // wave 1 publishes its partials; wave 0 merges and finishes
    if (w2 == 1) {
        if (half == 0) s_acc[qslot][sub] = acc;
        if ((t & 63) == 0) { s_z[qslot] = Z; s_m[qslot] = m; s_b[qslot] = best; }
    }
    __syncthreads();

    if (w2 == 0) {
        const float4 ao = s_acc[qslot][sub];
        const float Zo = s_z[qslot];
        const float mo = s_m[qslot];
        const int   bo = s_b[qslot];
        const bool takeOther = (mo > m) || (mo == m && bo < best);
        best = takeOther ? bo : best;
        Z += Zo;
        acc.x += ao.x; acc.y += ao.y; acc.z += ao.z; acc.w += ao.w;

        const float inv = 1.f / Z;
        if (half == 0) {
            float4 sv;
            sv.x = acc.x * inv; sv.y = acc.y * inv;
            sv.z = acc.z * inv; sv.w = acc.w * inv;
            s_acc[qslot][sub] = sv;       // channel-group index == sub
            if (sub == 0) out1[q] = (float)best;
        }
        // same-wave DS ordering makes the write visible to both halves below

        // final: out[dp] = sum_c s[c]*Wout[c][dp] + bout[dp] + 2*query[q][dp]
        // split-K across the two halves: half0 sums cg 0..15, half1 cg 16..31
        const int dpb = sub * 4;
        float4 r = {0.f, 0.f, 0.f, 0.f};
        if (half == 0) {
            const float4 b4 = *(const float4*)(bout + dpb);
            const float4 q4 = *(const float4*)(query + (size_t)q * EMBED + dpb);
            r.x = fmaf(2.f, q4.x, b4.x);
            r.y = fmaf(2.f, q4.y, b4.y);
            r.z = fmaf(2.f, q4.z, b4.z);
            r.w = fmaf(2.f, q4.w, b4.w);
        }
        const float4* srow = s_acc[qslot];
        const int cg0 = half * 16;
#pragma unroll 4
        for (int cg = cg0; cg < cg0 + 16; ++cg) {
            const float4 s4 = srow[cg];
            const float4 w0 = *(const float4*)(Wout + (size_t)(cg * 4 + 0) * EMBED + dpb);
            const float4 w1 = *(const float4*)(Wout + (size_t)(cg * 4 + 1) * EMBED + dpb);
            const float4 w2v = *(const float4*)(Wout + (size_t)(cg * 4 + 2) * EMBED + dpb);
            const float4 w3 = *(const float4*)(Wout + (size_t)(cg * 4 + 3) * EMBED + dpb);
            r.x = fmaf(s4.x, w0.x, r.x); r.y = fmaf(s4.x, w0.y, r.y);
            r.z = fmaf(s4.x, w0.z, r.z); r.w = fmaf(s4.x, w0.w, r.w);
            r.x = fmaf(s4.y, w1.x, r.x); r.y = fmaf(s4.y, w1.y, r.y);
            r.z = fmaf(s4.y, w1.z, r.z); r.w = fmaf(s4.y, w1.w, r.w);
            r.x = fmaf(s4.z, w2v.x, r.x); r.y = fmaf(s4.z, w2v.y, r.y);
            r.z = fmaf(s4.z, w2v.z, r.z); r.w = fmaf(s4.z, w2v.w, r.w);
            r.x = fmaf(s4.w, w3.x, r.x); r.y = fmaf(s4.w, w3.y, r.y);
            r.z = fmaf(s4.w, w3.z, r.z); r.w = fmaf(s4.w, w3.w, r.w);
        }
        // combine the two half-sums and store from half 0
        {
            const float rx = __shfl_xor(r.x, 32, 64);
            const float ry = __shfl_xor(r.y, 32, 64);
            const float rz = __shfl_xor(r.z, 32, 64);
            const float rw = __shfl_xor(r.w, 32, 64);
            r.x += rx; r.y += ry; r.z += rz; r.w += rw;
        }
        if (half == 0)
            *(float4*)(out0 + (size_t)q * EMBED + dpb) = r;
    }
}

// ---------------------------------------------------------------------------
extern "C" void kernel_launch(void* const* d_in, const int* in_sizes, int n_in,
                              void* d_out, int out_size, void* d_ws, size_t ws_size,
                              hipStream_t stream) {
    const float* query = (const float*)d_in[0];
    const float* value = (const float*)d_in[1];
    const float* refp  = (const float*)d_in[2];
    const float* Woff  = (const float*)d_in[3];
    const float* boff  = (const float*)d_in[4];
    const float* Wattn = (const float*)d_in[5];
    const float* battn = (const float*)d_in[6];
    const float* Wval  = (const float*)d_in[7];
    const float* bval  = (const float*)d_in[8];
    const float* Wout  = (const float*)d_in[9];
    const float* bout  = (const float*)d_in[10];
    const float* Wproj = (const float*)d_in[11];
    // d_in[12] = b_proj: level-constant -> cancels in softmax/argmax, unused.

    float* ws = (float*)d_ws;
    float* ws_v   = ws;                                   // NSLOT*128 padded map
    float* ws_off = ws_v + (size_t)NSLOT * EMBED;         // NQ*64
    float* ws_aw  = ws_off + (size_t)NQ * 64;             // NQ*32
    float* ws_u   = ws_aw + (size_t)NQ * 32;              // 128

    float* out0 = (float*)d_out;
    float* out1 = out0 + (size_t)NQ * EMBED;

    hipLaunchKernelGGL(k_prep, dim3(GRID_A + GRID_B + 1), dim3(256), 0, stream,
                       value, Wval, bval, query, Woff, boff, Wattn, battn,
                       Wout, Wproj, ws_v, ws_off, ws_aw, ws_u);
    hipLaunchKernelGGL(k_main, dim3(NQ / 2), dim3(256), 0, stream,
                       query, refp, ws_off, ws_aw, ws_v, ws_u, Wout, bout,
                       out0, out1);
}